// Round 5
// baseline (574.971 us; speedup 1.0000x reference)
//
#include <hip/hip_runtime.h>
#include <math.h>

#define BATCH 16

typedef __attribute__((ext_vector_type(8))) short s16x8;
typedef __attribute__((ext_vector_type(8))) unsigned short u16x8;
typedef __attribute__((ext_vector_type(4))) float f32x4;
typedef __attribute__((ext_vector_type(16))) float f32x16;

__device__ inline unsigned short f2bf_rn(float f) {
  unsigned u = __float_as_uint(f);
  u += 0x7FFF + ((u >> 16) & 1);
  return (unsigned short)(u >> 16);
}
__device__ inline float bf2f(unsigned short h) {
  return __uint_as_float(((unsigned)h) << 16);
}

// Async global->LDS DMA, 16B per lane. LDS dest is wave-uniform base + lane*16.
__device__ __forceinline__ void gload16(const unsigned short* g, unsigned short* l) {
  __builtin_amdgcn_global_load_lds(
      (__attribute__((address_space(1))) void*)g,
      (__attribute__((address_space(3))) void*)l, 16, 0, 0);
}

// ---------------------------------------------------------------------------
// Elementwise fp32 -> (bf16 hi, bf16 lo) split, 4 elems/thread.
// Three sources in one dispatch: edit (16384 blocks), src (16384), W (1024).
// ---------------------------------------------------------------------------
__global__ __launch_bounds__(256) void cvt_split3(
    const float* __restrict__ X0, unsigned short* __restrict__ H0,
    unsigned short* __restrict__ L0, const float* __restrict__ X1,
    unsigned short* __restrict__ H1, unsigned short* __restrict__ L1,
    const float* __restrict__ X2, unsigned short* __restrict__ H2,
    unsigned short* __restrict__ L2) {
  const int bid = blockIdx.x;
  const float* X;
  unsigned short *H, *L;
  size_t base;
  if (bid < 16384) { X = X0; H = H0; L = L0; base = (size_t)bid << 8; }
  else if (bid < 32768) { X = X1; H = H1; L = L1; base = (size_t)(bid - 16384) << 8; }
  else { X = X2; H = H2; L = L2; base = (size_t)(bid - 32768) << 8; }
  const size_t i = (base + threadIdx.x) << 2;
  f32x4 v = *(const f32x4*)(X + i);
  ushort4 h, l;
  h.x = f2bf_rn(v[0]); l.x = f2bf_rn(v[0] - bf2f(h.x));
  h.y = f2bf_rn(v[1]); l.y = f2bf_rn(v[1] - bf2f(h.y));
  h.z = f2bf_rn(v[2]); l.z = f2bf_rn(v[2] - bf2f(h.z));
  h.w = f2bf_rn(v[3]); l.w = f2bf_rn(v[3] - bf2f(h.w));
  *(ushort4*)(H + i) = h;
  *(ushort4*)(L + i) = l;
}

// ---------------------------------------------------------------------------
// 256x256-tile phase-split GEMM, C = A*B^T, 32x32x16 MFMA.
// HILO=1: split-bf16 3-MFMA fp32-accurate product (A=(AH,AL), B=(BH,BL)).
// SPLIT_OUT=1: write C as (CH,CL) bf16 hi/lo; else fp32 C.
// BK=32, 8 waves (2M x 4N), per-wave 128x64 = 4x2 tiles of 32x32.
// LDS 128KiB (HILO)/64KiB; staging via global_load_lds with slot-XOR swizzle
// (slot ^= (row>>1)&3) on global source AND frag read (conflict-free per
// 16-lane quarter-wave: 2 lanes/bank; r1/r3/r4 measured cnf=0).
// Operand layouts (32x32x16 bf16):
//   A/B frag: row(col)=lane&31, k=(lane>>5)*8 + j  (8 bf16 = 4 VGPR)
//   C/D     : col=lane&31, row=(reg&3)+8*(reg>>2)+4*(lane>>5)  [m74/m101]
// Loop, 2 phases per K-tile (k-half 0/16), 4 barriers — structure identical
// to round 3/4 (validated): {frag reads; (prefetch); s_barrier; setprio(1);
// MFMA cluster; setprio(0); s_barrier/syncthreads}. One vmcnt drain per tile.
// Grid: flat 256 blocks (1/CU), bijective XCD swizzle.
// ---------------------------------------------------------------------------
template <int HILO, int SPLIT_OUT>
__global__ __launch_bounds__(512, 2) void gemm8p(
    const unsigned short* __restrict__ AH, const unsigned short* __restrict__ AL,
    const unsigned short* __restrict__ BH, const unsigned short* __restrict__ BL,
    void* __restrict__ Cout, void* __restrict__ CoutL,
    long long sA, long long sB, long long sC, int batched) {
  constexpr int NARR = HILO ? 4 : 2;  // 0=AH,1=BH,2=AL,3=BL
  __shared__ __align__(16) unsigned short lds[2][NARR][8192];  // [dbuf][arr][256*32]
  const int tid = threadIdx.x;
  // XCD swizzle: 256 blocks -> 32 consecutive tiles per XCD
  const int wg = ((blockIdx.x & 7) << 5) | (blockIdx.x >> 3);
  int z, bm, bn;
  if (batched) {  // 16 batches x 4x4 tiles of 1024^2
    z = wg >> 4; bm = ((wg >> 2) & 3) << 8; bn = (wg & 3) << 8;
  } else {        // M=16384 flat x N=1024: 64x4 tiles
    z = 0; bm = (wg >> 2) << 8; bn = (wg & 3) << 8;
  }
  const int wave = tid >> 6, lane = tid & 63;
  const int wm = wave >> 2, wn = wave & 3;      // 2 x 4 wave grid
  const int lane31 = lane & 31, lhi = lane >> 5;

  // Staging addresses: 512 threads cover 128 rows x 64B per issue (q=0/1).
  const int svrow = tid >> 2;                                  // 0..127
  const int scol = ((tid & 3) ^ ((tid >> 3) & 3)) << 3;        // swizzled k-slot
  const unsigned short* gA0 = AH + (size_t)z * sA + (size_t)(bm + svrow) * 1024 + scol;
  const unsigned short* gB0 = BH + (size_t)z * sB + (size_t)(bn + svrow) * 1024 + scol;
  const unsigned short* gA1 = HILO ? (AL + (size_t)z * sA + (size_t)(bm + svrow) * 1024 + scol) : gA0;
  const unsigned short* gB1 = HILO ? (BL + (size_t)z * sB + (size_t)(bn + svrow) * 1024 + scol) : gB0;
  const int lwb = wave << 9;  // wave's 16-row LDS chunk base (shorts), q adds 4096

  // Fragment-read offsets [tile][k-half] (loop-invariant, swizzle matches
  // staging). slot = kh*2 + lhi; offset = row*32 + ((slot^((row>>1)&3))<<3).
  int aoff[4][2], boff[2][2];
#pragma unroll
  for (int mt = 0; mt < 4; mt++) {
    const int r = (wm << 7) + (mt << 5) + lane31;
#pragma unroll
    for (int kh = 0; kh < 2; kh++)
      aoff[mt][kh] = (r << 5) + ((((kh << 1) + lhi) ^ ((r >> 1) & 3)) << 3);
  }
#pragma unroll
  for (int nt = 0; nt < 2; nt++) {
    const int r = (wn << 6) + (nt << 5) + lane31;
#pragma unroll
    for (int kh = 0; kh < 2; kh++)
      boff[nt][kh] = (r << 5) + ((((kh << 1) + lhi) ^ ((r >> 1) & 3)) << 3);
  }

  f32x16 acc[4][2];
#pragma unroll
  for (int mt = 0; mt < 4; mt++)
#pragma unroll
    for (int nt = 0; nt < 2; nt++) acc[mt][nt] = (f32x16)(0.f);

#define ISS(NXT, ARR, G, Q, KO) \
  gload16((G) + ((size_t)(Q) << 17) + (KO), &lds[NXT][ARR][((Q) << 12) + lwb])

  // Prologue: stage tile 0 into buf 0, drain, barrier.
  ISS(0, 0, gA0, 0, 0); ISS(0, 0, gA0, 1, 0);
  ISS(0, 1, gB0, 0, 0); ISS(0, 1, gB0, 1, 0);
  if (HILO) {
    ISS(0, 2, gA1, 0, 0); ISS(0, 2, gA1, 1, 0);
    ISS(0, 3, gB1, 0, 0); ISS(0, 3, gB1, 1, 0);
  }
  __syncthreads();

#pragma unroll 1
  for (int kt = 0; kt < 32; ++kt) {
    const int cur = kt & 1, nxt = cur ^ 1;
    const int kn = (kt + 1) << 5;  // next tile k-offset (shorts)
    const bool pf = kt < 31;
    const unsigned short* LAH = lds[cur][0];
    const unsigned short* LBH = lds[cur][1];
    const unsigned short* LAL = lds[cur][HILO ? 2 : 0];
    const unsigned short* LBL = lds[cur][HILO ? 3 : 1];
    s16x8 ah[4], al[4], bh[2], bl[2];

#define LDFRAGS(KH)                                                      \
  do {                                                                   \
    _Pragma("unroll") for (int m_ = 0; m_ < 4; m_++) {                   \
      ah[m_] = *(const s16x8*)&LAH[aoff[m_][KH]];                        \
      if (HILO) al[m_] = *(const s16x8*)&LAL[aoff[m_][KH]];              \
    }                                                                    \
    _Pragma("unroll") for (int n_ = 0; n_ < 2; n_++) {                   \
      bh[n_] = *(const s16x8*)&LBH[boff[n_][KH]];                        \
      if (HILO) bl[n_] = *(const s16x8*)&LBL[boff[n_][KH]];              \
    }                                                                    \
  } while (0)
// MFMA cluster for one k-half, grouped by product term: within each group
// all 8 MFMAs hit distinct accs (independent); per-acc term order is
// al*bh, ah*bl, ah*bh per k-half (same compensation structure as before).
#define MMK()                                                                    \
  do {                                                                           \
    if (HILO) {                                                                  \
      _Pragma("unroll") for (int m_ = 0; m_ < 4; m_++)                           \
          _Pragma("unroll") for (int n_ = 0; n_ < 2; n_++)                       \
              acc[m_][n_] = __builtin_amdgcn_mfma_f32_32x32x16_bf16(             \
                  al[m_], bh[n_], acc[m_][n_], 0, 0, 0);                         \
      _Pragma("unroll") for (int m_ = 0; m_ < 4; m_++)                           \
          _Pragma("unroll") for (int n_ = 0; n_ < 2; n_++)                       \
              acc[m_][n_] = __builtin_amdgcn_mfma_f32_32x32x16_bf16(             \
                  ah[m_], bl[n_], acc[m_][n_], 0, 0, 0);                         \
    }                                                                            \
    _Pragma("unroll") for (int m_ = 0; m_ < 4; m_++)                             \
        _Pragma("unroll") for (int n_ = 0; n_ < 2; n_++)                         \
            acc[m_][n_] = __builtin_amdgcn_mfma_f32_32x32x16_bf16(               \
                ah[m_], bh[n_], acc[m_][n_], 0, 0, 0);                           \
  } while (0)

    // ---- phase 0: k-half 0 frags; issue ALL prefetch of kt+1
    LDFRAGS(0);
    if (pf) {
      ISS(nxt, 0, gA0, 0, kn); ISS(nxt, 0, gA0, 1, kn);
      ISS(nxt, 1, gB0, 0, kn); ISS(nxt, 1, gB0, 1, kn);
      if (HILO) {
        ISS(nxt, 2, gA1, 0, kn); ISS(nxt, 2, gA1, 1, kn);
        ISS(nxt, 3, gB1, 0, kn); ISS(nxt, 3, gB1, 1, kn);
      }
    }
    __builtin_amdgcn_s_barrier();
    __builtin_amdgcn_s_setprio(1); MMK(); __builtin_amdgcn_s_setprio(0);
    __builtin_amdgcn_s_barrier();

    // ---- phase 1: k-half 1 frags
    LDFRAGS(1);
    __builtin_amdgcn_s_barrier();
    __builtin_amdgcn_s_setprio(1); MMK(); __builtin_amdgcn_s_setprio(0);
    // Iteration end: drain prefetch (issued ~1 tile of compute ago -> cheap),
    // barrier frees buf[cur] for the next tile's prefetch.
    __syncthreads();
#undef LDFRAGS
#undef MMK
  }
#undef ISS

  // Epilogue. C/D layout (32x32x16, verified): col=lane&31,
  // row=(reg&3)+8*(reg>>2)+4*(lane>>5). Per (mt,reg): 32 lanes -> 128B run.
  const int crow0 = bm + (wm << 7) + (lhi << 2);
  const int ccol0 = bn + (wn << 6) + lane31;
  if (SPLIT_OUT) {
    unsigned short* CH = (unsigned short*)Cout + (size_t)z * sC;
    unsigned short* CL = (unsigned short*)CoutL + (size_t)z * sC;
#pragma unroll
    for (int mt = 0; mt < 4; mt++)
#pragma unroll
      for (int reg = 0; reg < 16; reg++) {
        const int row = crow0 + (mt << 5) + (reg & 3) + ((reg >> 2) << 3);
        const size_t base = (size_t)row * 1024 + ccol0;
#pragma unroll
        for (int nt = 0; nt < 2; nt++) {
          float f = acc[mt][nt][reg];
          unsigned short h = f2bf_rn(f);
          CH[base + (nt << 5)] = h;
          CL[base + (nt << 5)] = f2bf_rn(f - bf2f(h));
        }
      }
  } else {
    float* C = (float*)Cout + (size_t)z * sC;
#pragma unroll
    for (int mt = 0; mt < 4; mt++)
#pragma unroll
      for (int reg = 0; reg < 16; reg++) {
        const int row = crow0 + (mt << 5) + (reg & 3) + ((reg >> 2) << 3);
        float* cp = C + (size_t)row * 1024 + ccol0;
#pragma unroll
        for (int nt = 0; nt < 2; nt++) cp[nt << 5] = acc[mt][nt][reg];
      }
  }
}

// ---------------------------------------------------------------------------
// Wave reductions
// ---------------------------------------------------------------------------
__device__ inline float waveMax(float v) {
#pragma unroll
  for (int o = 32; o > 0; o >>= 1) v = fmaxf(v, __shfl_down(v, o, 64));
  return v;
}
__device__ inline float waveSum(float v) {
#pragma unroll
  for (int o = 32; o > 0; o >>= 1) v += __shfl_down(v, o, 64);
  return v;
}

// ---------------------------------------------------------------------------
// edit_weights = masked row softmax(sim) -> bf16. One block per (b,e) row.
// ---------------------------------------------------------------------------
__global__ __launch_bounds__(256) void row_softmax_kernel(
    const float* __restrict__ sim, const int* __restrict__ smask,
    unsigned short* __restrict__ out) {
  const int row = blockIdx.x;  // b*1024 + e
  const int b = row >> 10;
  const float* x = sim + ((size_t)row << 10);
  const int* mk = smask + (b << 10);
  const int t = threadIdx.x;

  float4 v = ((const float4*)x)[t];
  int4 m = ((const int4*)mk)[t];
  float vv[4] = {v.x, v.y, v.z, v.w};
  const int mmv[4] = {m.x, m.y, m.z, m.w};

  float mx = -3.0e38f;
#pragma unroll
  for (int i = 0; i < 4; i++)
    if (!mmv[i]) mx = fmaxf(mx, vv[i]);

  __shared__ float red[4];
  float wmx = waveMax(mx);
  const int wave = t >> 6;
  if ((t & 63) == 0) red[wave] = wmx;
  __syncthreads();
  mx = fmaxf(fmaxf(red[0], red[1]), fmaxf(red[2], red[3]));
  __syncthreads();

  float s = 0.f;
#pragma unroll
  for (int i = 0; i < 4; i++) {
    float e = mmv[i] ? 0.f : __expf(vv[i] - mx);
    vv[i] = e;
    s += e;
  }
  float ws = waveSum(s);
  if ((t & 63) == 0) red[wave] = ws;
  __syncthreads();
  s = red[0] + red[1] + red[2] + red[3];
  float inv = 1.0f / s;

  ushort4 o;
  o.x = f2bf_rn(vv[0] * inv);
  o.y = f2bf_rn(vv[1] * inv);
  o.z = f2bf_rn(vv[2] * inv);
  o.w = f2bf_rn(vv[3] * inv);
  *(ushort4*)&out[((size_t)row << 10) + (t << 2)] = o;
}

// ---------------------------------------------------------------------------
// Col-softmax phase A: partial (max, sum) over 64-row e-chunks.
// ---------------------------------------------------------------------------
__global__ __launch_bounds__(256) void col_partial(
    const float* __restrict__ sim, const int* __restrict__ emask,
    float* __restrict__ pmax, float* __restrict__ psum) {
  const int b = blockIdx.z;
  const int ec = blockIdx.y;
  const int l = (blockIdx.x << 8) + threadIdx.x;
  const float* p = sim + ((size_t)b << 20) + (((size_t)ec << 6) << 10) + l;
  const int* mk = emask + (b << 10) + (ec << 6);
  float mx0 = -1.0e30f, s0 = 0.f, mx1 = -1.0e30f, s1 = 0.f;
#pragma unroll 4
  for (int i = 0; i < 64; i += 2) {
    float v0 = mk[i] ? -3.0e38f : p[(size_t)i << 10];
    float v1 = mk[i + 1] ? -3.0e38f : p[(size_t)(i + 1) << 10];
    float n0 = fmaxf(mx0, v0);
    s0 = s0 * __expf(mx0 - n0) + __expf(v0 - n0);
    mx0 = n0;
    float n1 = fmaxf(mx1, v1);
    s1 = s1 * __expf(mx1 - n1) + __expf(v1 - n1);
    mx1 = n1;
  }
  float M = fmaxf(mx0, mx1);
  float S = s0 * __expf(mx0 - M) + s1 * __expf(mx1 - M);
  const int o = (((b << 4) + ec) << 10) + l;
  pmax[o] = M;
  psum[o] = S;
}

// ---------------------------------------------------------------------------
// Col-softmax phase C: combine partials; write TRANSPOSED bf16 wT[b][l][e].
// ---------------------------------------------------------------------------
__global__ __launch_bounds__(256) void col_weights_T(
    const float* __restrict__ sim, const int* __restrict__ emask,
    const float* __restrict__ pmax, const float* __restrict__ psum,
    unsigned short* __restrict__ wT) {
  const int b = blockIdx.z;
  const int l0 = blockIdx.x << 6;
  const int e0 = blockIdx.y << 6;
  const int t = threadIdx.x;
  __shared__ float Ml[64], Il[64];
  __shared__ int msk[64];
  __shared__ float gm[4][64], gs[4][64];
  __shared__ unsigned short tile[64][72];

  {
    const int ll = t & 63, g = t >> 6;
    float m = -1.0e30f, s = 0.f;
#pragma unroll
    for (int q = 0; q < 4; q++) {
      int ec = g + (q << 2);
      const int o = (((b << 4) + ec) << 10) + l0 + ll;
      float pm = pmax[o], ps = psum[o];
      float nm = fmaxf(m, pm);
      s = s * __expf(m - nm) + ps * __expf(pm - nm);
      m = nm;
    }
    gm[g][ll] = m;
    gs[g][ll] = s;
    __syncthreads();
    if (t < 64) {
      float M = fmaxf(fmaxf(gm[0][t], gm[1][t]), fmaxf(gm[2][t], gm[3][t]));
      float S = 0.f;
#pragma unroll
      for (int q = 0; q < 4; q++) S += gs[q][t] * __expf(gm[q][t] - M);
      Ml[t] = M;
      Il[t] = 1.0f / S;
      msk[t] = emask[(b << 10) + e0 + t];
    }
    __syncthreads();
  }

  const int lane = t & 63, wv = t >> 6;
#pragma unroll
  for (int i = 0; i < 16; i++) {
    const int el = (wv << 4) + i;
    float v = sim[((size_t)b << 20) + ((size_t)(e0 + el) << 10) + l0 + lane];
    float w = msk[el] ? 0.f : __expf(v - Ml[lane]) * Il[lane];
    tile[lane][el] = f2bf_rn(w);
  }
  __syncthreads();
  const int r = t >> 2, seg = (t & 3) << 4;
  u16x8 v0 = *(const u16x8*)&tile[r][seg];
  u16x8 v1 = *(const u16x8*)&tile[r][seg + 8];
  size_t o = ((size_t)((b << 10) + l0 + r) << 10) + e0 + seg;
  *(u16x8*)&wT[o] = v0;
  *(u16x8*)&wT[o + 8] = v1;
}

// ---------------------------------------------------------------------------
// bf16 64x64 transpose: XT[b][d][l] = X[b][l][d].
// ---------------------------------------------------------------------------
__global__ __launch_bounds__(256) void transpose16(
    const unsigned short* __restrict__ X, unsigned short* __restrict__ XT) {
  __shared__ unsigned short ts[64][72];
  const int b = blockIdx.z;
  const int d0 = blockIdx.x << 6, l0 = blockIdx.y << 6;
  const int t = threadIdx.x;
  const unsigned short* Xb = X + ((size_t)b << 20);
  unsigned short* Tb = XT + ((size_t)b << 20);
  const int row = t >> 2, seg = (t & 3) << 4;
  u16x8 v0 = *(const u16x8*)&Xb[((size_t)(l0 + row) << 10) + d0 + seg];
  u16x8 v1 = *(const u16x8*)&Xb[((size_t)(l0 + row) << 10) + d0 + seg + 8];
#pragma unroll
  for (int i = 0; i < 8; i++) ts[seg + i][row] = v0[i];
#pragma unroll
  for (int i = 0; i < 8; i++) ts[seg + 8 + i][row] = v1[i];
  __syncthreads();
  u16x8 o0 = *(const u16x8*)&ts[row][seg];
  u16x8 o1 = *(const u16x8*)&ts[row][seg + 8];
  size_t o = ((size_t)(d0 + row) << 10) + l0 + seg;
  *(u16x8*)&Tb[o] = o0;
  *(u16x8*)&Tb[o + 8] = o1;
}

// ---------------------------------------------------------------------------
// Buffer plan (ws = 128 MB, d_out = 128 MB used as scratch until outputs):
//  ws[0,32):    editH                 (live until editT transpose)
//  ws[32,64):   srcH  -> editT        (after srcT transpose consumes srcH)
//  ws[64,96):   projH -> wE
//  ws[96,128):  projL -> wST
//  dout[0,32):  editL -> sim(lo half) -> out_edit
//  dout[32,64):          sim(hi half) -> out_edit
//  dout[64,96): srcL  -> pmax/psum(2MB) -> srcT -> out_src
//  dout[96,100): WH,WL                 -> out_src
// ---------------------------------------------------------------------------
extern "C" void kernel_launch(void* const* d_in, const int* in_sizes, int n_in,
                              void* d_out, int out_size, void* d_ws,
                              size_t ws_size, hipStream_t stream) {
  const float* edit = (const float*)d_in[0];
  const float* src = (const float*)d_in[1];
  const int* emask = (const int*)d_in[2];
  const int* smask = (const int*)d_in[3];
  const float* W = (const float*)d_in[4];

  char* ws = (char*)d_ws;
  char* dob = (char*)d_out;

  unsigned short* eH = (unsigned short*)ws;
  unsigned short* sH = (unsigned short*)(ws + ((size_t)32 << 20));
  unsigned short* pH = (unsigned short*)(ws + ((size_t)64 << 20));
  unsigned short* pL = (unsigned short*)(ws + ((size_t)96 << 20));
  unsigned short* wE = pH;     // after proj GEMM consumed
  unsigned short* wST = pL;
  unsigned short* editT = sH;  // after srcH consumed by its transpose

  unsigned short* eL = (unsigned short*)dob;
  unsigned short* sL = (unsigned short*)(dob + ((size_t)64 << 20));
  unsigned short* WH = (unsigned short*)(dob + ((size_t)96 << 20));
  unsigned short* WL = (unsigned short*)(dob + ((size_t)98 << 20));
  float* sim = (float*)dob;  // [0,64)
  float* pmax = (float*)(dob + ((size_t)64 << 20));
  float* psum = (float*)(dob + ((size_t)65 << 20));
  unsigned short* srcT = (unsigned short*)(dob + ((size_t)64 << 20));
  float* out_edit = (float*)dob;
  float* out_src = (float*)(dob + ((size_t)64 << 20));

  const long long S1 = 1LL << 20;
  dim3 blk(256), blk512(512);

  // P1: split conversions (edit + src + W in one dispatch)
  cvt_split3<<<dim3(33792), blk, 0, stream>>>(edit, eH, eL, src, sH, sL, W, WH, WL);

  // P2: proj = edit @ W^T -> hi/lo bf16 (M=16384 flattened, N=1024)
  gemm8p<1, 1><<<dim3(256), blk512, 0, stream>>>(
      eH, eL, WH, WL, (void*)pH, (void*)pL, 0, 0, 0, 0);

  // P3: sim[b] = proj[b] @ src[b]^T -> fp32 (in d_out[0,64MB))
  gemm8p<1, 0><<<dim3(256), blk512, 0, stream>>>(
      pH, pL, sH, sL, (void*)sim, nullptr, S1, S1, S1, 1);

  // P4: softmaxes
  row_softmax_kernel<<<dim3(BATCH << 10), blk, 0, stream>>>(sim, smask, wE);
  col_partial<<<dim3(4, 16, BATCH), blk, 0, stream>>>(sim, emask, pmax, psum);
  col_weights_T<<<dim3(16, 16, BATCH), blk, 0, stream>>>(sim, emask, pmax, psum, wST);

  // P5: transposes, SEQUENTIAL (srcT reads sH; editT then overwrites sH)
  transpose16<<<dim3(16, 16, BATCH), blk, 0, stream>>>(sH, srcT);
  transpose16<<<dim3(16, 16, BATCH), blk, 0, stream>>>(eH, editT);

  // P6: ctx GEMMs. edit_ctx FIRST (reads srcT in dout[64,96) before src_ctx
  // overwrites it; writes dout[0,64) over dead sim).
  gemm8p<0, 0><<<dim3(256), blk512, 0, stream>>>(
      wE, nullptr, srcT, nullptr, (void*)out_edit, nullptr, S1, S1, S1, 1);
  gemm8p<0, 0><<<dim3(256), blk512, 0, stream>>>(
      wST, nullptr, editT, nullptr, (void*)out_src, nullptr, S1, S1, S1, 1);
}

// Round 6
// 548.836 us; speedup vs baseline: 1.0476x; 1.0476x over previous
//
#include <hip/hip_runtime.h>
#include <math.h>

#define BATCH 16

typedef __attribute__((ext_vector_type(8))) short s16x8;
typedef __attribute__((ext_vector_type(8))) unsigned short u16x8;
typedef __attribute__((ext_vector_type(4))) float f32x4;

__device__ inline unsigned short f2bf_rn(float f) {
  unsigned u = __float_as_uint(f);
  u += 0x7FFF + ((u >> 16) & 1);
  return (unsigned short)(u >> 16);
}
__device__ inline float bf2f(unsigned short h) {
  return __uint_as_float(((unsigned)h) << 16);
}

// Async global->LDS DMA, 16B per lane. LDS dest is wave-uniform base + lane*16.
__device__ __forceinline__ void gload16(const unsigned short* g, unsigned short* l) {
  __builtin_amdgcn_global_load_lds(
      (__attribute__((address_space(1))) void*)g,
      (__attribute__((address_space(3))) void*)l, 16, 0, 0);
}

// ---------------------------------------------------------------------------
// Elementwise fp32 -> (bf16 hi, bf16 lo) split, 4 elems/thread.
// Three sources in one dispatch: edit (16384 blocks), src (16384), W (1024).
// ---------------------------------------------------------------------------
__global__ __launch_bounds__(256) void cvt_split3(
    const float* __restrict__ X0, unsigned short* __restrict__ H0,
    unsigned short* __restrict__ L0, const float* __restrict__ X1,
    unsigned short* __restrict__ H1, unsigned short* __restrict__ L1,
    const float* __restrict__ X2, unsigned short* __restrict__ H2,
    unsigned short* __restrict__ L2) {
  const int bid = blockIdx.x;
  const float* X;
  unsigned short *H, *L;
  size_t base;
  if (bid < 16384) { X = X0; H = H0; L = L0; base = (size_t)bid << 8; }
  else if (bid < 32768) { X = X1; H = H1; L = L1; base = (size_t)(bid - 16384) << 8; }
  else { X = X2; H = H2; L = L2; base = (size_t)(bid - 32768) << 8; }
  const size_t i = (base + threadIdx.x) << 2;
  f32x4 v = *(const f32x4*)(X + i);
  ushort4 h, l;
  h.x = f2bf_rn(v[0]); l.x = f2bf_rn(v[0] - bf2f(h.x));
  h.y = f2bf_rn(v[1]); l.y = f2bf_rn(v[1] - bf2f(h.y));
  h.z = f2bf_rn(v[2]); l.z = f2bf_rn(v[2] - bf2f(h.z));
  h.w = f2bf_rn(v[3]); l.w = f2bf_rn(v[3] - bf2f(h.w));
  *(ushort4*)(H + i) = h;
  *(ushort4*)(L + i) = l;
}

// ---------------------------------------------------------------------------
// 256x256-tile GEMM with COUNTED-vmcnt pipeline (T3+T4+T5), C = A*B^T.
// 16x16x32 MFMA (conflict-free frag pattern, r1/r3/r4: cnf=0).
// HILO=1: split-bf16 3-MFMA fp32-accurate product (A=(AH,AL), B=(BH,BL)).
// SPLIT_OUT=1: write C as (CH,CL) bf16 hi/lo; else fp32 C.
// BK=32, 8 waves (2M x 4N), per-wave 128x64, LDS 128KiB (HILO)/64KiB.
// Staging via global_load_lds, slot-XOR swizzle (slot ^= (row>>1)&3) on
// global source AND frag read.
// Schedule per K-tile kt (2 barriers, NO vmcnt(0) drain in main loop):
//   entry: s_waitcnt vmcnt(8|4)  -> T_kt landed (issued 1.5 tiles ago);
//          s_barrier              -> all waves agree buf[cur] ready
//   LDA4(0)+LDBALL; setprio(1) MMQ(0) setprio(0)
//   LDA4(1); lgkmcnt(0)+sched_barrier; s_barrier  -> all reads of buf[cur] done
//   STAGE T_{kt+2} into buf[cur]  (stays in flight across next barriers)
//   setprio(1) MMQ(1) setprio(0)
// Grid: flat 256 blocks (1/CU), bijective XCD swizzle.
// ---------------------------------------------------------------------------
template <int HILO, int SPLIT_OUT>
__global__ __launch_bounds__(512, 2) void gemm8p(
    const unsigned short* __restrict__ AH, const unsigned short* __restrict__ AL,
    const unsigned short* __restrict__ BH, const unsigned short* __restrict__ BL,
    void* __restrict__ Cout, void* __restrict__ CoutL,
    long long sA, long long sB, long long sC, int batched) {
  constexpr int NARR = HILO ? 4 : 2;  // 0=AH,1=BH,2=AL,3=BL
  __shared__ __align__(16) unsigned short lds[2][NARR][8192];  // [dbuf][arr][256*32]
  const int tid = threadIdx.x;
  // XCD swizzle: 256 blocks -> 32 consecutive tiles per XCD
  const int wg = ((blockIdx.x & 7) << 5) | (blockIdx.x >> 3);
  int z, bm, bn;
  if (batched) {  // 16 batches x 4x4 tiles of 1024^2
    z = wg >> 4; bm = ((wg >> 2) & 3) << 8; bn = (wg & 3) << 8;
  } else {        // M=16384 flat x N=1024: 64x4 tiles
    z = 0; bm = (wg >> 2) << 8; bn = (wg & 3) << 8;
  }
  const int wave = tid >> 6, lane = tid & 63;
  const int wm = wave >> 2, wn = wave & 3;      // 2 x 4 wave grid
  const int fr = lane & 15, fks = lane >> 4;    // frag row, k-slot

  // Staging addresses: 512 threads cover 128 rows x 64B per issue (q=0/1).
  const int svrow = tid >> 2;                                  // 0..127
  const int scol = ((tid & 3) ^ ((tid >> 3) & 3)) << 3;        // swizzled k-slot
  const unsigned short* gA0 = AH + (size_t)z * sA + (size_t)(bm + svrow) * 1024 + scol;
  const unsigned short* gB0 = BH + (size_t)z * sB + (size_t)(bn + svrow) * 1024 + scol;
  const unsigned short* gA1 = HILO ? (AL + (size_t)z * sA + (size_t)(bm + svrow) * 1024 + scol) : gA0;
  const unsigned short* gB1 = HILO ? (BL + (size_t)z * sB + (size_t)(bn + svrow) * 1024 + scol) : gB0;
  const int lwb = wave << 9;  // wave's 16-row LDS chunk base (shorts), q adds 4096

  // Fragment-read offsets (loop-invariant, swizzle matches staging)
  int aoff[8], boff[4];
#pragma unroll
  for (int m = 0; m < 8; m++) {
    const int r = (wm << 7) + (m << 4) + fr;
    aoff[m] = (r << 5) + ((fks ^ ((r >> 1) & 3)) << 3);
  }
#pragma unroll
  for (int n = 0; n < 4; n++) {
    const int r = (wn << 6) + (n << 4) + fr;
    boff[n] = (r << 5) + ((fks ^ ((r >> 1) & 3)) << 3);
  }

  f32x4 acc[8][4];
#pragma unroll
  for (int m = 0; m < 8; m++)
#pragma unroll
    for (int n = 0; n < 4; n++) acc[m][n] = (f32x4)(0.f);

#define ISS(BUF, ARR, G, Q, KO) \
  gload16((G) + ((size_t)(Q) << 17) + (KO), &lds[BUF][ARR][((Q) << 12) + lwb])
#define STAGE(BUF, KO)                                  \
  do {                                                  \
    ISS(BUF, 0, gA0, 0, KO); ISS(BUF, 0, gA0, 1, KO);   \
    ISS(BUF, 1, gB0, 0, KO); ISS(BUF, 1, gB0, 1, KO);   \
    if (HILO) {                                         \
      ISS(BUF, 2, gA1, 0, KO); ISS(BUF, 2, gA1, 1, KO); \
      ISS(BUF, 3, gB1, 0, KO); ISS(BUF, 3, gB1, 1, KO); \
    }                                                   \
  } while (0)

  // Prologue: stage tiles 0 and 1 (16|8 loads in flight; no drain).
  STAGE(0, 0);
  STAGE(1, 32);

#pragma unroll 1
  for (int kt = 0; kt < 32; ++kt) {
    const int cur = kt & 1;
    const unsigned short* LAH = lds[cur][0];
    const unsigned short* LBH = lds[cur][1];
    const unsigned short* LAL = lds[cur][HILO ? 2 : 0];
    const unsigned short* LBL = lds[cur][HILO ? 3 : 1];
    s16x8 ah[4], al[4], bh[4], bl[4];

#define LDA4(QM)                                                         \
  do {                                                                   \
    _Pragma("unroll") for (int m_ = 0; m_ < 4; m_++) {                   \
      const int o_ = aoff[((QM) << 2) + m_];                             \
      ah[m_] = *(const s16x8*)&LAH[o_];                                  \
      if (HILO) al[m_] = *(const s16x8*)&LAL[o_];                        \
    }                                                                    \
  } while (0)
#define LDBALL()                                                         \
  do {                                                                   \
    _Pragma("unroll") for (int n_ = 0; n_ < 4; n_++) {                   \
      const int o_ = boff[n_];                                           \
      bh[n_] = *(const s16x8*)&LBH[o_];                                  \
      if (HILO) bl[n_] = *(const s16x8*)&LBL[o_];                        \
    }                                                                    \
  } while (0)
// MFMA cluster for one QM half, grouped by product term (16 independent
// MFMAs between dependent acc reuses); per-acc term order al*bh, ah*bl,
// ah*bh — identical to rounds 3/4 (bit-exact).
#define MMQ(QM)                                                                  \
  do {                                                                           \
    if (HILO) {                                                                  \
      _Pragma("unroll") for (int m_ = 0; m_ < 4; m_++)                           \
          _Pragma("unroll") for (int n_ = 0; n_ < 4; n_++)                       \
              acc[((QM) << 2) + m_][n_] =                                        \
          __builtin_amdgcn_mfma_f32_16x16x32_bf16(al[m_], bh[n_],                \
                                                  acc[((QM) << 2) + m_][n_], 0, 0, 0); \
      _Pragma("unroll") for (int m_ = 0; m_ < 4; m_++)                           \
          _Pragma("unroll") for (int n_ = 0; n_ < 4; n_++)                       \
              acc[((QM) << 2) + m_][n_] =                                        \
          __builtin_amdgcn_mfma_f32_16x16x32_bf16(ah[m_], bl[n_],                \
                                                  acc[((QM) << 2) + m_][n_], 0, 0, 0); \
    }                                                                            \
    _Pragma("unroll") for (int m_ = 0; m_ < 4; m_++)                             \
        _Pragma("unroll") for (int n_ = 0; n_ < 4; n_++)                         \
            acc[((QM) << 2) + m_][n_] =                                          \
        __builtin_amdgcn_mfma_f32_16x16x32_bf16(ah[m_], bh[n_],                  \
                                                acc[((QM) << 2) + m_][n_], 0, 0, 0);   \
  } while (0)

    // ---- entry: T_kt landed (counted wait, T_{kt+1} stays in flight)
    if (kt < 31) {
      if (HILO) asm volatile("s_waitcnt vmcnt(8)" ::: "memory");
      else      asm volatile("s_waitcnt vmcnt(4)" ::: "memory");
    } else {
      asm volatile("s_waitcnt vmcnt(0)" ::: "memory");
    }
    __builtin_amdgcn_s_barrier();

    // ---- phase 0: QM=0 A frags + all B frags; MFMA cluster
    LDA4(0); LDBALL();
    __builtin_amdgcn_s_setprio(1); MMQ(0); __builtin_amdgcn_s_setprio(0);

    // ---- phase 1: QM=1 A frags; then free buf[cur] and restage it
    LDA4(1);
    asm volatile("s_waitcnt lgkmcnt(0)" ::: "memory");
    __builtin_amdgcn_sched_barrier(0);
    __builtin_amdgcn_s_barrier();  // all waves' reads of buf[cur] retired
    if (kt < 30) STAGE(cur, (kt + 2) << 5);
    __builtin_amdgcn_s_setprio(1); MMQ(1); __builtin_amdgcn_s_setprio(0);
#undef LDA4
#undef LDBALL
#undef MMQ
  }
#undef ISS
#undef STAGE

  const int cr = (lane >> 4) << 2;
  const int crow0 = bm + (wm << 7);
  const int ccol0 = bn + (wn << 6);
  if (SPLIT_OUT) {
    unsigned short* CH = (unsigned short*)Cout + (size_t)z * sC;
    unsigned short* CL = (unsigned short*)CoutL + (size_t)z * sC;
#pragma unroll
    for (int m = 0; m < 8; m++)
#pragma unroll
      for (int r = 0; r < 4; r++) {
        const size_t base = (size_t)(crow0 + (m << 4) + cr + r) * 1024 + ccol0 + fr;
#pragma unroll
        for (int n = 0; n < 4; n++) {
          float f = acc[m][n][r];
          unsigned short h = f2bf_rn(f);
          CH[base + (n << 4)] = h;
          CL[base + (n << 4)] = f2bf_rn(f - bf2f(h));
        }
      }
  } else {
    float* C = (float*)Cout + (size_t)z * sC;
#pragma unroll
    for (int m = 0; m < 8; m++)
#pragma unroll
      for (int r = 0; r < 4; r++) {
        float* cp = C + (size_t)(crow0 + (m << 4) + cr + r) * 1024 + ccol0 + fr;
#pragma unroll
        for (int n = 0; n < 4; n++) cp[n << 4] = acc[m][n][r];
      }
  }
}

// ---------------------------------------------------------------------------
// Wave reductions
// ---------------------------------------------------------------------------
__device__ inline float waveMax(float v) {
#pragma unroll
  for (int o = 32; o > 0; o >>= 1) v = fmaxf(v, __shfl_down(v, o, 64));
  return v;
}
__device__ inline float waveSum(float v) {
#pragma unroll
  for (int o = 32; o > 0; o >>= 1) v += __shfl_down(v, o, 64);
  return v;
}

// ---------------------------------------------------------------------------
// edit_weights = masked row softmax(sim) -> bf16. One block per (b,e) row.
// ---------------------------------------------------------------------------
__global__ __launch_bounds__(256) void row_softmax_kernel(
    const float* __restrict__ sim, const int* __restrict__ smask,
    unsigned short* __restrict__ out) {
  const int row = blockIdx.x;  // b*1024 + e
  const int b = row >> 10;
  const float* x = sim + ((size_t)row << 10);
  const int* mk = smask + (b << 10);
  const int t = threadIdx.x;

  float4 v = ((const float4*)x)[t];
  int4 m = ((const int4*)mk)[t];
  float vv[4] = {v.x, v.y, v.z, v.w};
  const int mmv[4] = {m.x, m.y, m.z, m.w};

  float mx = -3.0e38f;
#pragma unroll
  for (int i = 0; i < 4; i++)
    if (!mmv[i]) mx = fmaxf(mx, vv[i]);

  __shared__ float red[4];
  float wmx = waveMax(mx);
  const int wave = t >> 6;
  if ((t & 63) == 0) red[wave] = wmx;
  __syncthreads();
  mx = fmaxf(fmaxf(red[0], red[1]), fmaxf(red[2], red[3]));
  __syncthreads();

  float s = 0.f;
#pragma unroll
  for (int i = 0; i < 4; i++) {
    float e = mmv[i] ? 0.f : __expf(vv[i] - mx);
    vv[i] = e;
    s += e;
  }
  float ws = waveSum(s);
  if ((t & 63) == 0) red[wave] = ws;
  __syncthreads();
  s = red[0] + red[1] + red[2] + red[3];
  float inv = 1.0f / s;

  ushort4 o;
  o.x = f2bf_rn(vv[0] * inv);
  o.y = f2bf_rn(vv[1] * inv);
  o.z = f2bf_rn(vv[2] * inv);
  o.w = f2bf_rn(vv[3] * inv);
  *(ushort4*)&out[((size_t)row << 10) + (t << 2)] = o;
}

// ---------------------------------------------------------------------------
// Col-softmax phase A: partial (max, sum) over 64-row e-chunks.
// ---------------------------------------------------------------------------
__global__ __launch_bounds__(256) void col_partial(
    const float* __restrict__ sim, const int* __restrict__ emask,
    float* __restrict__ pmax, float* __restrict__ psum) {
  const int b = blockIdx.z;
  const int ec = blockIdx.y;
  const int l = (blockIdx.x << 8) + threadIdx.x;
  const float* p = sim + ((size_t)b << 20) + (((size_t)ec << 6) << 10) + l;
  const int* mk = emask + (b << 10) + (ec << 6);
  float mx0 = -1.0e30f, s0 = 0.f, mx1 = -1.0e30f, s1 = 0.f;
#pragma unroll 4
  for (int i = 0; i < 64; i += 2) {
    float v0 = mk[i] ? -3.0e38f : p[(size_t)i << 10];
    float v1 = mk[i + 1] ? -3.0e38f : p[(size_t)(i + 1) << 10];
    float n0 = fmaxf(mx0, v0);
    s0 = s0 * __expf(mx0 - n0) + __expf(v0 - n0);
    mx0 = n0;
    float n1 = fmaxf(mx1, v1);
    s1 = s1 * __expf(mx1 - n1) + __expf(v1 - n1);
    mx1 = n1;
  }
  float M = fmaxf(mx0, mx1);
  float S = s0 * __expf(mx0 - M) + s1 * __expf(mx1 - M);
  const int o = (((b << 4) + ec) << 10) + l;
  pmax[o] = M;
  psum[o] = S;
}

// ---------------------------------------------------------------------------
// Col-softmax phase C: combine partials; write TRANSPOSED bf16 wT[b][l][e].
// ---------------------------------------------------------------------------
__global__ __launch_bounds__(256) void col_weights_T(
    const float* __restrict__ sim, const int* __restrict__ emask,
    const float* __restrict__ pmax, const float* __restrict__ psum,
    unsigned short* __restrict__ wT) {
  const int b = blockIdx.z;
  const int l0 = blockIdx.x << 6;
  const int e0 = blockIdx.y << 6;
  const int t = threadIdx.x;
  __shared__ float Ml[64], Il[64];
  __shared__ int msk[64];
  __shared__ float gm[4][64], gs[4][64];
  __shared__ unsigned short tile[64][72];

  {
    const int ll = t & 63, g = t >> 6;
    float m = -1.0e30f, s = 0.f;
#pragma unroll
    for (int q = 0; q < 4; q++) {
      int ec = g + (q << 2);
      const int o = (((b << 4) + ec) << 10) + l0 + ll;
      float pm = pmax[o], ps = psum[o];
      float nm = fmaxf(m, pm);
      s = s * __expf(m - nm) + ps * __expf(pm - nm);
      m = nm;
    }
    gm[g][ll] = m;
    gs[g][ll] = s;
    __syncthreads();
    if (t < 64) {
      float M = fmaxf(fmaxf(gm[0][t], gm[1][t]), fmaxf(gm[2][t], gm[3][t]));
      float S = 0.f;
#pragma unroll
      for (int q = 0; q < 4; q++) S += gs[q][t] * __expf(gm[q][t] - M);
      Ml[t] = M;
      Il[t] = 1.0f / S;
      msk[t] = emask[(b << 10) + e0 + t];
    }
    __syncthreads();
  }

  const int lane = t & 63, wv = t >> 6;
#pragma unroll
  for (int i = 0; i < 16; i++) {
    const int el = (wv << 4) + i;
    float v = sim[((size_t)b << 20) + ((size_t)(e0 + el) << 10) + l0 + lane];
    float w = msk[el] ? 0.f : __expf(v - Ml[lane]) * Il[lane];
    tile[lane][el] = f2bf_rn(w);
  }
  __syncthreads();
  const int r = t >> 2, seg = (t & 3) << 4;
  u16x8 v0 = *(const u16x8*)&tile[r][seg];
  u16x8 v1 = *(const u16x8*)&tile[r][seg + 8];
  size_t o = ((size_t)((b << 10) + l0 + r) << 10) + e0 + seg;
  *(u16x8*)&wT[o] = v0;
  *(u16x8*)&wT[o + 8] = v1;
}

// ---------------------------------------------------------------------------
// bf16 64x64 transpose: XT[b][d][l] = X[b][l][d].
// ---------------------------------------------------------------------------
__global__ __launch_bounds__(256) void transpose16(
    const unsigned short* __restrict__ X, unsigned short* __restrict__ XT) {
  __shared__ unsigned short ts[64][72];
  const int b = blockIdx.z;
  const int d0 = blockIdx.x << 6, l0 = blockIdx.y << 6;
  const int t = threadIdx.x;
  const unsigned short* Xb = X + ((size_t)b << 20);
  unsigned short* Tb = XT + ((size_t)b << 20);
  const int row = t >> 2, seg = (t & 3) << 4;
  u16x8 v0 = *(const u16x8*)&Xb[((size_t)(l0 + row) << 10) + d0 + seg];
  u16x8 v1 = *(const u16x8*)&Xb[((size_t)(l0 + row) << 10) + d0 + seg + 8];
#pragma unroll
  for (int i = 0; i < 8; i++) ts[seg + i][row] = v0[i];
#pragma unroll
  for (int i = 0; i < 8; i++) ts[seg + 8 + i][row] = v1[i];
  __syncthreads();
  u16x8 o0 = *(const u16x8*)&ts[row][seg];
  u16x8 o1 = *(const u16x8*)&ts[row][seg + 8];
  size_t o = ((size_t)(d0 + row) << 10) + l0 + seg;
  *(u16x8*)&Tb[o] = o0;
  *(u16x8*)&Tb[o + 8] = o1;
}

// ---------------------------------------------------------------------------
// Buffer plan (ws = 128 MB, d_out = 128 MB used as scratch until outputs):
//  ws[0,32):    editH                 (live until editT transpose)
//  ws[32,64):   srcH  -> editT        (after srcT transpose consumes srcH)
//  ws[64,96):   projH -> wE
//  ws[96,128):  projL -> wST
//  dout[0,32):  editL -> sim(lo half) -> out_edit
//  dout[32,64):          sim(hi half) -> out_edit
//  dout[64,96): srcL  -> pmax/psum(2MB) -> srcT -> out_src
//  dout[96,100): WH,WL                 -> out_src
// ---------------------------------------------------------------------------
extern "C" void kernel_launch(void* const* d_in, const int* in_sizes, int n_in,
                              void* d_out, int out_size, void* d_ws,
                              size_t ws_size, hipStream_t stream) {
  const float* edit = (const float*)d_in[0];
  const float* src = (const float*)d_in[1];
  const int* emask = (const int*)d_in[2];
  const int* smask = (const int*)d_in[3];
  const float* W = (const float*)d_in[4];

  char* ws = (char*)d_ws;
  char* dob = (char*)d_out;

  unsigned short* eH = (unsigned short*)ws;
  unsigned short* sH = (unsigned short*)(ws + ((size_t)32 << 20));
  unsigned short* pH = (unsigned short*)(ws + ((size_t)64 << 20));
  unsigned short* pL = (unsigned short*)(ws + ((size_t)96 << 20));
  unsigned short* wE = pH;     // after proj GEMM consumed
  unsigned short* wST = pL;
  unsigned short* editT = sH;  // after srcH consumed by its transpose

  unsigned short* eL = (unsigned short*)dob;
  unsigned short* sL = (unsigned short*)(dob + ((size_t)64 << 20));
  unsigned short* WH = (unsigned short*)(dob + ((size_t)96 << 20));
  unsigned short* WL = (unsigned short*)(dob + ((size_t)98 << 20));
  float* sim = (float*)dob;  // [0,64)
  float* pmax = (float*)(dob + ((size_t)64 << 20));
  float* psum = (float*)(dob + ((size_t)65 << 20));
  unsigned short* srcT = (unsigned short*)(dob + ((size_t)64 << 20));
  float* out_edit = (float*)dob;
  float* out_src = (float*)(dob + ((size_t)64 << 20));

  const long long S1 = 1LL << 20;
  dim3 blk(256), blk512(512);

  // P1: split conversions (edit + src + W in one dispatch)
  cvt_split3<<<dim3(33792), blk, 0, stream>>>(edit, eH, eL, src, sH, sL, W, WH, WL);

  // P2: proj = edit @ W^T -> hi/lo bf16 (M=16384 flattened, N=1024)
  gemm8p<1, 1><<<dim3(256), blk512, 0, stream>>>(
      eH, eL, WH, WL, (void*)pH, (void*)pL, 0, 0, 0, 0);

  // P3: sim[b] = proj[b] @ src[b]^T -> fp32 (in d_out[0,64MB))
  gemm8p<1, 0><<<dim3(256), blk512, 0, stream>>>(
      pH, pL, sH, sL, (void*)sim, nullptr, S1, S1, S1, 1);

  // P4: softmaxes
  row_softmax_kernel<<<dim3(BATCH << 10), blk, 0, stream>>>(sim, smask, wE);
  col_partial<<<dim3(4, 16, BATCH), blk, 0, stream>>>(sim, emask, pmax, psum);
  col_weights_T<<<dim3(16, 16, BATCH), blk, 0, stream>>>(sim, emask, pmax, psum, wST);

  // P5: transposes, SEQUENTIAL (srcT reads sH; editT then overwrites sH)
  transpose16<<<dim3(16, 16, BATCH), blk, 0, stream>>>(sH, srcT);
  transpose16<<<dim3(16, 16, BATCH), blk, 0, stream>>>(eH, editT);

  // P6: ctx GEMMs. edit_ctx FIRST (reads srcT in dout[64,96) before src_ctx
  // overwrites it; writes dout[0,64) over dead sim).
  gemm8p<0, 0><<<dim3(256), blk512, 0, stream>>>(
      wE, nullptr, srcT, nullptr, (void*)out_edit, nullptr, S1, S1, S1, 1);
  gemm8p<0, 0><<<dim3(256), blk512, 0, stream>>>(
      wST, nullptr, editT, nullptr, (void*)out_src, nullptr, S1, S1, S1, 1);
}